// Round 2
// baseline (249.869 us; speedup 1.0000x reference)
//
#include <hip/hip_runtime.h>

typedef short  s16x8 __attribute__((ext_vector_type(8)));
typedef float  f32x4 __attribute__((ext_vector_type(4)));
typedef float  f32x2 __attribute__((ext_vector_type(2)));
typedef unsigned short u16x4 __attribute__((ext_vector_type(4)));

#define D_FEAT     256
#define KE         288            // 256 features + 4 norm slots + 28 zero pad
#define KSTEPS     9              // 288 / 32
#define N_SAMP     4096
#define N_TRAIN    65536
#define NCHUNK     16
#define SBLK       128            // samples per workgroup (32 per wave)
#define ROWS_ITER  64             // train rows staged per block-iteration
#define CHUNK_ROWS (N_TRAIN / NCHUNK)   // 4096
#define NITER      (CHUNK_ROWS / ROWS_ITER) // 64
#define ROW_BYTES  (KE * 2)       // 576
#define WAVE_TILE  (KSTEPS * 1024) // 9216 B staged per wave per iter
#define BUF_BYTES  (4 * WAVE_TILE) // 36864 B per buffer

__device__ __forceinline__ unsigned short f2bf(float f) {
  unsigned int u = __builtin_bit_cast(unsigned int, f);
  u += 0x7FFFu + ((u >> 16) & 1u);     // round-to-nearest-even
  return (unsigned short)(u >> 16);
}

// ---------------- prep: fp32 [rows][256] -> bf16 ext [rows][288] ----------------
// ext slots (train): [256..259] = {-n_hi, -n_lo, 1, 1};  (sample): {1, 1, -n_hi, -n_lo}
// where n = ||row||^2 / 2, hi/lo bf16 split. Cross terms under the GEMM give
// t = x.y - ||x||^2/2 - ||y||^2/2 = -d^2/2 directly out of the MFMA accumulator.
__global__ __launch_bounds__(256) void prep_ext(const float* __restrict__ X,
                                                unsigned short* __restrict__ E,
                                                int nrows, int train_mode) {
  int wv = threadIdx.x >> 6, ln = threadIdx.x & 63;
  int row = blockIdx.x * 4 + wv;
  if (row >= nrows) return;
  const float4* xr = (const float4*)(X + (size_t)row * D_FEAT);
  float4 v = xr[ln];
  float ss = v.x * v.x + v.y * v.y + v.z * v.z + v.w * v.w;
#pragma unroll
  for (int m = 32; m; m >>= 1) ss += __shfl_xor(ss, m);
  float ax = 0.5f * ss;
  u16x4 o;
  o[0] = f2bf(v.x); o[1] = f2bf(v.y); o[2] = f2bf(v.z); o[3] = f2bf(v.w);
  ((u16x4*)(E + (size_t)row * KE))[ln] = o;
  if (ln < 8) {
    u16x4 e = {0, 0, 0, 0};
    if (ln == 0) {
      unsigned short hi = f2bf(ax);
      float hif = __builtin_bit_cast(float, ((unsigned int)hi) << 16);
      unsigned short lo = f2bf(ax - hif);
      unsigned short nhi = (unsigned short)(hi ^ 0x8000u);
      unsigned short nlo = (unsigned short)(lo ^ 0x8000u);
      const unsigned short one = 0x3F80u;
      if (train_mode) { e[0] = nhi; e[1] = nlo; e[2] = one; e[3] = one; }
      else           { e[0] = one; e[1] = one; e[2] = nhi; e[3] = nlo; }
    }
    ((u16x4*)(E + (size_t)row * KE + D_FEAT))[ln] = e;
  }
}

// ---------------- main: MFMA GEMM + online top-2 ----------------
// Block = 4 waves, 128 samples. Each wave holds 2x9 sample B-fragments in regs.
// Per iter: each wave stages 16 train rows (9x global_load_lds dwordx4, LDS layout
// pre-permuted to fragment order so ds_read_b128 is linear/conflict-free), all
// waves consume all 64 rows. Double-buffered, counted vmcnt, raw s_barrier.
__global__ __launch_bounds__(256, 2) void topk_gemm(const unsigned short* __restrict__ Aext,
                                                    const unsigned short* __restrict__ Bext,
                                                    f32x2* __restrict__ partials) {
  __shared__ __attribute__((aligned(16))) char smem[2 * BUF_BYTES]; // 72 KiB
  const int tid = threadIdx.x;
  const int wv = tid >> 6, ln = tid & 63;
  const int lrow = ln & 15, lgrp = ln >> 4;
  const int sb = blockIdx.x;   // 0..31 sample block
  const int ch = blockIdx.y;   // 0..15 train chunk

  // hoist sample fragments: B-operand layout = col(lane&15)=sample, k-octet=lane>>4
  s16x8 sf0[KSTEPS], sf1[KSTEPS];
  {
    const char* a0 = (const char*)Aext +
                     (size_t)(sb * SBLK + wv * 32 + lrow) * ROW_BYTES + lgrp * 16;
#pragma unroll
    for (int kk = 0; kk < KSTEPS; kk++) {
      sf0[kk] = *(const s16x8*)(a0 + kk * 64);
      sf1[kk] = *(const s16x8*)(a0 + 16 * ROW_BYTES + kk * 64);
    }
  }

  const char* bsrc = (const char*)Bext +
                     ((size_t)ch * CHUNK_ROWS + wv * 16 + lrow) * ROW_BYTES + lgrp * 16;

  float b0a = -3.0e38f, b1a = -3.0e38f, b0b = -3.0e38f, b1b = -3.0e38f;

  auto stage = [&](int buf, const char* src) {
    char* ldsbase = smem + buf * BUF_BYTES + wv * WAVE_TILE;
#pragma unroll
    for (int j = 0; j < KSTEPS; j++) {
      __builtin_amdgcn_global_load_lds(
          (__attribute__((address_space(1))) void*)(src + j * 64),
          (__attribute__((address_space(3))) void*)(ldsbase + j * 1024),
          16, 0, 0);
    }
  };

  stage(0, bsrc);
  const char* src = bsrc + (size_t)ROWS_ITER * ROW_BYTES;

  for (int it = 0; it < NITER; ++it) {
    const int cur = it & 1;
    if (it + 1 < NITER) {
      stage(cur ^ 1, src);
      src += (size_t)ROWS_ITER * ROW_BYTES;
      asm volatile("s_waitcnt vmcnt(9)" ::: "memory");   // own prev stage done, prefetch in flight
    } else {
      asm volatile("s_waitcnt vmcnt(0)" ::: "memory");
    }
    __builtin_amdgcn_s_barrier();                        // all waves' stage(it) done
    asm volatile("" ::: "memory");

    const char* lds = smem + cur * BUF_BYTES;
#pragma unroll
    for (int at = 0; at < 4; ++at) {
      f32x4 acc0 = {0.f, 0.f, 0.f, 0.f}, acc1 = {0.f, 0.f, 0.f, 0.f};
#pragma unroll
      for (int kk = 0; kk < KSTEPS; kk++) {
        s16x8 af = *(const s16x8*)(lds + at * WAVE_TILE + kk * 1024 + ln * 16);
        acc0 = __builtin_amdgcn_mfma_f32_16x16x32_bf16(af, sf0[kk], acc0, 0, 0, 0);
        acc1 = __builtin_amdgcn_mfma_f32_16x16x32_bf16(af, sf1[kk], acc1, 0, 0, 0);
      }
      // acc[r] = t = -d^2/2 for (train row, sample col); online top-2 (largest t)
#pragma unroll
      for (int r = 0; r < 4; r++) {
        float t0 = acc0[r], t1 = acc1[r];
        float n0 = fmaxf(t0, b0a); b1a = fmaxf(fminf(t0, b0a), b1a); b0a = n0;
        float m0 = fmaxf(t1, b0b); b1b = fmaxf(fminf(t1, b0b), b1b); b0b = m0;
      }
    }
    asm volatile("s_waitcnt lgkmcnt(0)" ::: "memory");   // all ds_reads of bufc retired
    __builtin_amdgcn_s_barrier();                        // nobody overwrites bufc early
    asm volatile("" ::: "memory");
  }

  // merge across the 4 lane-groups (same sample, different train rows)
#pragma unroll
  for (int m = 16; m <= 32; m <<= 1) {
    float o0 = __shfl_xor(b0a, m), o1 = __shfl_xor(b1a, m);
    float t = fmaxf(b0a, o0);
    b1a = fmaxf(fminf(b0a, o0), fmaxf(b1a, o1));
    b0a = t;
    o0 = __shfl_xor(b0b, m); o1 = __shfl_xor(b1b, m);
    t = fmaxf(b0b, o0);
    b1b = fmaxf(fminf(b0b, o0), fmaxf(b1b, o1));
    b0b = t;
  }
  if (lgrp == 0) {
    int s0 = sb * SBLK + wv * 32 + lrow;
    f32x2 pa = {b0a, b1a}, pb = {b0b, b1b};
    partials[(size_t)ch * N_SAMP + s0] = pa;
    partials[(size_t)ch * N_SAMP + s0 + 16] = pb;
  }
}

// ---------------- final merge + ratio, single block ----------------
__global__ __launch_bounds__(1024) void reduce_final(const f32x2* __restrict__ partials,
                                                     float* __restrict__ out) {
  __shared__ int wsum[16];
  int tid = threadIdx.x;
  int cnt = 0;
#pragma unroll
  for (int rep = 0; rep < 4; ++rep) {
    int s = rep * 1024 + tid;
    float b0 = -3.0e38f, b1 = -3.0e38f;
#pragma unroll
    for (int c = 0; c < NCHUNK; c++) {
      f32x2 p = partials[(size_t)c * N_SAMP + s];
      float t = fmaxf(b0, p[0]);
      b1 = fmaxf(fminf(b0, p[0]), fmaxf(b1, p[1]));
      b0 = t;
    }
    float d0 = sqrtf(fmaxf(-2.0f * b0, 0.0f));
    float d1 = sqrtf(fmaxf(-2.0f * b1, 0.0f));
    out[2 * s] = d0;
    out[2 * s + 1] = d1;
    cnt += (d0 < (1.0f / 3.0f) * d1) ? 1 : 0;
  }
#pragma unroll
  for (int m = 32; m; m >>= 1) cnt += __shfl_xor(cnt, m);
  if ((tid & 63) == 0) wsum[tid >> 6] = cnt;
  __syncthreads();
  if (tid == 0) {
    int tot = 0;
#pragma unroll
    for (int i = 0; i < 16; i++) tot += wsum[i];
    out[2 * N_SAMP] = (float)tot * (1.0f / (float)N_SAMP);
  }
}

extern "C" void kernel_launch(void* const* d_in, const int* in_sizes, int n_in,
                              void* d_out, int out_size, void* d_ws, size_t ws_size,
                              hipStream_t stream) {
  const float* Xs = (const float*)d_in[0];   // X_sample [4096][256]
  const float* Xt = (const float*)d_in[1];   // X_train  [65536][256]
  unsigned short* Bext = (unsigned short*)d_ws;                 // 65536*288 bf16 = 36 MiB
  unsigned short* Aext = Bext + (size_t)N_TRAIN * KE;           // 4096*288 bf16
  f32x2* partials = (f32x2*)(Aext + (size_t)N_SAMP * KE);       // 16*4096 pairs
  float* out = (float*)d_out;

  prep_ext<<<N_TRAIN / 4, 256, 0, stream>>>(Xt, Bext, N_TRAIN, 1);
  prep_ext<<<N_SAMP / 4, 256, 0, stream>>>(Xs, Aext, N_SAMP, 0);
  topk_gemm<<<dim3(N_SAMP / SBLK, NCHUNK), 256, 0, stream>>>(Aext, Bext, partials);
  reduce_final<<<1, 1024, 0, stream>>>(partials, out);
}

// Round 3
// 242.858 us; speedup vs baseline: 1.0289x; 1.0289x over previous
//
#include <hip/hip_runtime.h>

typedef short  s16x8  __attribute__((ext_vector_type(8)));
typedef float  f32x16 __attribute__((ext_vector_type(16)));
typedef float  f32x2  __attribute__((ext_vector_type(2)));
typedef unsigned short u16x4 __attribute__((ext_vector_type(4)));

#define D_FEAT     256
#define KE         288                  // 256 features + 4 norm slots + 28 zero pad
#define KF         18                   // K fragments of 16 (288/16)
#define N_SAMP     4096
#define N_TRAIN    65536
#define NCHUNK     32
#define CHUNK_ROWS (N_TRAIN / NCHUNK)   // 2048
#define ROWS_ITER  128                  // train rows staged per block-iteration
#define NITER      (CHUNK_ROWS / ROWS_ITER) // 16
#define ROW_BYTES  (KE * 2)             // 576
#define BUF_BYTES  (ROWS_ITER * ROW_BYTES)  // 73728 per buffer
#define NREGION    (BUF_BYTES / 1024)   // 72 = 4 tiles x 18 kf
#define LPW        9                    // stage loads per wave (72/8)

__device__ __forceinline__ unsigned short f2bf(float f) {
  unsigned int u = __builtin_bit_cast(unsigned int, f);
  u += 0x7FFFu + ((u >> 16) & 1u);
  return (unsigned short)(u >> 16);
}

// ---------------- prep: fp32 [rows][256] -> bf16 ext [rows][288] ----------------
// ext slots (train): {-n_hi,-n_lo,1,1}; (sample): {1,1,-n_hi,-n_lo}, n=||row||^2/2.
// GEMM then yields t = x.y - ||x||^2/2 - ||y||^2/2 = -d^2/2 directly.
__global__ __launch_bounds__(256) void prep_ext(const float* __restrict__ X,
                                                unsigned short* __restrict__ E,
                                                int nrows, int train_mode) {
  int wv = threadIdx.x >> 6, ln = threadIdx.x & 63;
  int row = blockIdx.x * 4 + wv;
  if (row >= nrows) return;
  const float4* xr = (const float4*)(X + (size_t)row * D_FEAT);
  float4 v = xr[ln];
  float ss = v.x * v.x + v.y * v.y + v.z * v.z + v.w * v.w;
#pragma unroll
  for (int m = 32; m; m >>= 1) ss += __shfl_xor(ss, m);
  float ax = 0.5f * ss;
  u16x4 o;
  o[0] = f2bf(v.x); o[1] = f2bf(v.y); o[2] = f2bf(v.z); o[3] = f2bf(v.w);
  ((u16x4*)(E + (size_t)row * KE))[ln] = o;
  if (ln < 8) {
    u16x4 e = {0, 0, 0, 0};
    if (ln == 0) {
      unsigned short hi = f2bf(ax);
      float hif = __builtin_bit_cast(float, ((unsigned int)hi) << 16);
      unsigned short lo = f2bf(ax - hif);
      unsigned short nhi = (unsigned short)(hi ^ 0x8000u);
      unsigned short nlo = (unsigned short)(lo ^ 0x8000u);
      const unsigned short one = 0x3F80u;
      if (train_mode) { e[0] = nhi; e[1] = nlo; e[2] = one; e[3] = one; }
      else           { e[0] = one; e[1] = one; e[2] = nhi; e[3] = nlo; }
    }
    ((u16x4*)(E + (size_t)row * KE + D_FEAT))[ln] = e;
  }
}

// ---------------- main: 32x32x16 MFMA GEMM + online top-2 ----------------
// 512-thr block (8 waves). Wave owns 64 samples: 2 register B-sets x 18 kf (144 VGPR).
// LDS: 128 train rows x 288 k, double-buffered (144 KiB), fragment-order regions of
// 1024 B: region r=(tile r/18, kf r%18), lane l = (row l&31, k-half l>>5), 16 B/lane.
// Each 1 KiB ds_read_b128 feeds 2 MFMAs (64 FLOP/LDS byte). Counted vmcnt(9).
__global__ __launch_bounds__(512, 2) void topk_gemm(const unsigned short* __restrict__ Aext,
                                                    const unsigned short* __restrict__ Bext,
                                                    f32x2* __restrict__ partials) {
  __shared__ __attribute__((aligned(16))) char smem[2 * BUF_BYTES]; // 144 KiB
  const int tid = threadIdx.x;
  const int wv = tid >> 6, ln = tid & 63;
  const int lc = ln & 31, lh = ln >> 5;
  const int ch = blockIdx.x;   // 0..31 train chunk  (XCD = ch%8 -> chunk L2-locality)
  const int sb = blockIdx.y;   // 0..7  sample block of 512

  // hoisted sample fragments: lane = (col l&31, k-half l>>5), 8 bf16 each
  s16x8 sf0[KF], sf1[KF];
  {
    const char* a0 = (const char*)Aext +
                     (size_t)(sb * 512 + wv * 64 + lc) * ROW_BYTES + lh * 16;
#pragma unroll
    for (int kk = 0; kk < KF; kk++) {
      sf0[kk] = *(const s16x8*)(a0 + kk * 32);
      sf1[kk] = *(const s16x8*)(a0 + 32 * ROW_BYTES + kk * 32);
    }
  }

  // staging: wave w owns regions r = w*9 .. w*9+8; source pre-permuted to region order
  int soff[LPW];
#pragma unroll
  for (int j = 0; j < LPW; ++j) {
    int r = wv * LPW + j;
    soff[j] = (r / KF) * (32 * ROW_BYTES) + (r % KF) * 32;
  }
  const char* srcb = (const char*)Bext +
                     ((size_t)ch * CHUNK_ROWS + lc) * ROW_BYTES + lh * 16;

  float b0a = -3.0e38f, b1a = -3.0e38f, b0b = -3.0e38f, b1b = -3.0e38f;

  auto stage = [&](int buf, int it) {
    const char* s = srcb + (size_t)it * BUF_BYTES;
    char* d = smem + buf * BUF_BYTES + (wv * LPW) * 1024;
#pragma unroll
    for (int j = 0; j < LPW; j++) {
      __builtin_amdgcn_global_load_lds(
          (const __attribute__((address_space(1))) void*)(s + soff[j]),
          (__attribute__((address_space(3))) void*)(d + j * 1024),
          16, 0, 0);
    }
  };

  stage(0, 0);

  for (int it = 0; it < NITER; ++it) {
    const int cur = it & 1;
    if (it + 1 < NITER) {
      stage(cur ^ 1, it + 1);
      asm volatile("s_waitcnt vmcnt(9)" ::: "memory");   // own stage(it) done, prefetch in flight
    } else {
      asm volatile("s_waitcnt vmcnt(0)" ::: "memory");
    }
    __builtin_amdgcn_s_barrier();                        // all waves' stage(it) visible
    asm volatile("" ::: "memory");

    const char* lds = smem + cur * BUF_BYTES;
#pragma unroll
    for (int at = 0; at < 4; ++at) {
      f32x16 acc0 = {0.f}, acc1 = {0.f};
#pragma unroll
      for (int r = 1; r < 16; r++) { acc0[r] = 0.f; acc1[r] = 0.f; }
#pragma unroll
      for (int kk = 0; kk < KF; kk++) {
        s16x8 av = *(const s16x8*)(lds + at * (KF * 1024) + kk * 1024 + ln * 16);
        acc0 = __builtin_amdgcn_mfma_f32_32x32x16_bf16(av, sf0[kk], acc0, 0, 0, 0);
        acc1 = __builtin_amdgcn_mfma_f32_32x32x16_bf16(av, sf1[kk], acc1, 0, 0, 0);
      }
      // lane holds 16 t-values (16 train rows) for sample col=lane&31; online top-2
#pragma unroll
      for (int r = 0; r < 16; r++) {
        float t0 = acc0[r], t1 = acc1[r];
        float n0 = fmaxf(t0, b0a); b1a = fmaxf(fminf(t0, b0a), b1a); b0a = n0;
        float m0 = fmaxf(t1, b0b); b1b = fmaxf(fminf(t1, b0b), b1b); b0b = m0;
      }
    }
    asm volatile("s_waitcnt lgkmcnt(0)" ::: "memory");   // all ds_reads of buf retired
    __builtin_amdgcn_s_barrier();                        // before anyone overwrites it
    asm volatile("" ::: "memory");
  }

  // lanes l and l+32 hold the same sample col (different row halves): one butterfly
  {
    float o0 = __shfl_xor(b0a, 32), o1 = __shfl_xor(b1a, 32);
    float t = fmaxf(b0a, o0);
    b1a = fmaxf(fminf(b0a, o0), fmaxf(b1a, o1));
    b0a = t;
    o0 = __shfl_xor(b0b, 32); o1 = __shfl_xor(b1b, 32);
    t = fmaxf(b0b, o0);
    b1b = fmaxf(fminf(b0b, o0), fmaxf(b1b, o1));
    b0b = t;
  }
  if (lh == 0) {
    int s0 = sb * 512 + wv * 64 + lc;
    f32x2 pa = {b0a, b1a}, pb = {b0b, b1b};
    partials[(size_t)ch * N_SAMP + s0] = pa;
    partials[(size_t)ch * N_SAMP + s0 + 32] = pb;
  }
}

// ---------------- final merge + ratio, single block ----------------
__global__ __launch_bounds__(1024) void reduce_final(const f32x2* __restrict__ partials,
                                                     float* __restrict__ out) {
  __shared__ int wsum[16];
  int tid = threadIdx.x;
  int cnt = 0;
#pragma unroll
  for (int rep = 0; rep < 4; ++rep) {
    int s = rep * 1024 + tid;
    float b0 = -3.0e38f, b1 = -3.0e38f;
    for (int c = 0; c < NCHUNK; c++) {
      f32x2 p = partials[(size_t)c * N_SAMP + s];
      float t = fmaxf(b0, p[0]);
      b1 = fmaxf(fminf(b0, p[0]), fmaxf(b1, p[1]));
      b0 = t;
    }
    float d0 = sqrtf(fmaxf(-2.0f * b0, 0.0f));
    float d1 = sqrtf(fmaxf(-2.0f * b1, 0.0f));
    out[2 * s] = d0;
    out[2 * s + 1] = d1;
    cnt += (d0 < (1.0f / 3.0f) * d1) ? 1 : 0;
  }
#pragma unroll
  for (int m = 32; m; m >>= 1) cnt += __shfl_xor(cnt, m);
  if ((tid & 63) == 0) wsum[tid >> 6] = cnt;
  __syncthreads();
  if (tid == 0) {
    int tot = 0;
#pragma unroll
    for (int i = 0; i < 16; i++) tot += wsum[i];
    out[2 * N_SAMP] = (float)tot * (1.0f / (float)N_SAMP);
  }
}

extern "C" void kernel_launch(void* const* d_in, const int* in_sizes, int n_in,
                              void* d_out, int out_size, void* d_ws, size_t ws_size,
                              hipStream_t stream) {
  const float* Xs = (const float*)d_in[0];   // X_sample [4096][256]
  const float* Xt = (const float*)d_in[1];   // X_train  [65536][256]
  unsigned short* Bext = (unsigned short*)d_ws;                 // 65536*288 bf16 = 36 MiB
  unsigned short* Aext = Bext + (size_t)N_TRAIN * KE;           // 4096*288 bf16
  f32x2* partials = (f32x2*)(Aext + (size_t)N_SAMP * KE);       // 32*4096 pairs = 1 MiB
  float* out = (float*)d_out;

  prep_ext<<<N_TRAIN / 4, 256, 0, stream>>>(Xt, Bext, N_TRAIN, 1);
  prep_ext<<<N_SAMP / 4, 256, 0, stream>>>(Xs, Aext, N_SAMP, 0);
  topk_gemm<<<dim3(NCHUNK, N_SAMP / 512), 512, 0, stream>>>(Aext, Bext, partials);
  reduce_final<<<1, 1024, 0, stream>>>(partials, out);
}